// Round 1
// baseline (275.275 us; speedup 1.0000x reference)
//
#include <hip/hip_runtime.h>

#define BATCH 64
#define D1 1024
#define D2 256
#define BLOCKS_PER_BATCH 64
#define THREADS 256
// per batch: 262144 triples = 786432 floats = 65536 groups of 12 floats (3 x float4)
// threads per batch = 64 blocks * 256 = 16384 -> 4 groups per thread, exact coverage

__global__ __launch_bounds__(THREADS) void score_sum_kernel(
        const float* __restrict__ z,
        const float* __restrict__ R,
        float* __restrict__ partial) {
    const int b = blockIdx.y;
    const int tid = blockIdx.x * THREADS + threadIdx.x;   // 0..16383 within batch

    const float Rb = R[b];
    const float Bc = -0.5f / (Rb * Rb);                   // -0.5 * A

    const float4* __restrict__ zb =
        (const float4*)(z + (size_t)b * ((size_t)D1 * D2 * 3));

    float acc = 0.0f;
#pragma unroll
    for (int g = 0; g < 4; ++g) {
        const int group = g * 16384 + tid;                // 0..65535
        const float4 v0 = zb[group * 3 + 0];
        const float4 v1 = zb[group * 3 + 1];
        const float4 v2 = zb[group * 3 + 2];
        // triples: (v0.x v0.y v0.z) (v0.w v1.x v1.y) (v1.z v1.w v2.x) (v2.y v2.z v2.w)
        const float n0 = sqrtf(fmaf(v0.x, v0.x, fmaf(v0.y, v0.y, v0.z * v0.z)));
        const float n1 = sqrtf(fmaf(v0.w, v0.w, fmaf(v1.x, v1.x, v1.y * v1.y)));
        const float n2 = sqrtf(fmaf(v1.z, v1.z, fmaf(v1.w, v1.w, v2.x * v2.x)));
        const float n3 = sqrtf(fmaf(v2.y, v2.y, fmaf(v2.z, v2.z, v2.w * v2.w)));
        acc += __expf(Bc * n0) + __expf(Bc * n1) + __expf(Bc * n2) + __expf(Bc * n3);
    }

    // wave (64) shuffle reduce, then cross-wave via LDS
    const int lane = threadIdx.x & 63;
    const int wave = threadIdx.x >> 6;
    for (int off = 32; off; off >>= 1) acc += __shfl_down(acc, off, 64);

    __shared__ float lds[THREADS / 64];
    if (lane == 0) lds[wave] = acc;
    __syncthreads();
    if (threadIdx.x == 0) {
        float s = lds[0] + lds[1] + lds[2] + lds[3];
        partial[b * BLOCKS_PER_BATCH + blockIdx.x] = s;
    }
}

// i0e(x) for x >= ~20 via the positive-term asymptotic series:
// i0e(x) = [1 + 1/(8x) + 9/(2!(8x)^2) + 225/(3!(8x)^3) + 11025/(4!(8x)^4)
//           + 893025/(5!(8x)^5)] / sqrt(2*pi*x)
// truncation < 1e-10 relative for x >= 100 (our A range is [100, 2500], 2A <= 5000)
__device__ inline double i0e_large(double x) {
    const double ix = 1.0 / x;
    const double s = 1.0 + ix * (0.125
                   + ix * (0.0703125
                   + ix * (0.0732421875
                   + ix * (0.112152099609375
                   + ix * 0.22711181640625))));
    return s / sqrt(6.283185307179586476925286766559 * x);
}

__global__ __launch_bounds__(64) void finalize_kernel(
        const float* __restrict__ partial,
        const float* __restrict__ R,
        const int* __restrict__ num_obs_p,
        float* __restrict__ out) {
    const int b = blockIdx.x;
    const int t = threadIdx.x;

    float v = partial[b * BLOCKS_PER_BATCH + t];
    for (int off = 32; off; off >>= 1) v += __shfl_down(v, off, 64);

    if (t == 0) {
        const double nobs = (double)num_obs_p[0];
        const double Rb = (double)R[b];
        const double A = 1.0 / (Rb * Rb);

        // 3D sphere moments
        const double e2 = exp(-2.0 * A);
        const double e4 = exp(-4.0 * A);
        const double mean3 = (1.0 - e2) / (2.0 * A);
        const double ms2_3 = (1.0 - e4) / (4.0 * A);
        const double var3 = ms2_3 - mean3 * mean3;

        // 2D circle moments via i0e
        const double i0eA  = i0e_large(A);
        const double i0e2A = i0e_large(2.0 * A);
        const double var2 = i0e2A - i0eA * i0eA;

        const double WT3 = 0.95, WT2 = 0.05;
        const double mu     = nobs * (WT3 * mean3 + WT2 * i0eA);
        const double sigma2 = nobs * (WT3 * var3  + WT2 * var2);
        const double raw    = (double)v;
        const double ALPHA = 1.0, BETA = 0.0;
        const double objective = raw - ALPHA * mu - BETA * sigma2;

        out[b]           = (float)raw;
        out[BATCH + b]   = (float)mu;
        out[2*BATCH + b] = (float)sigma2;
        out[3*BATCH + b] = (float)objective;
    }
}

extern "C" void kernel_launch(void* const* d_in, const int* in_sizes, int n_in,
                              void* d_out, int out_size, void* d_ws, size_t ws_size,
                              hipStream_t stream) {
    const float* z    = (const float*)d_in[0];
    const float* R    = (const float*)d_in[1];
    const int*   nobs = (const int*)d_in[2];
    float* out = (float*)d_out;
    float* partial = (float*)d_ws;   // BATCH * BLOCKS_PER_BATCH floats = 16 KB

    dim3 grid(BLOCKS_PER_BATCH, BATCH);
    score_sum_kernel<<<grid, THREADS, 0, stream>>>(z, R, partial);
    finalize_kernel<<<BATCH, 64, 0, stream>>>(partial, R, nobs, out);
}